// Round 10
// baseline (466.686 us; speedup 1.0000x reference)
//
#include <hip/hip_runtime.h>
#include <cstdint>

#define N_NODES 200000
#define N_EDGES 3200000
#define F_IN 128
#define CH 32
#define N_GRAPHS 1024
#define N_LABELS 17

#define BROWS 512                 // rows per bucket
#define NBUCK ((N_NODES + BROWS - 1) / BROWS)   // 391
#define CAP 10240                 // record capacity per bucket (mean 8192, sd ~90)
#define EPB 8192                  // edges per workgroup in pass A

typedef unsigned int uint32;
typedef unsigned short u16;

#define TSCALE 16.f               // int8 t-table fixed-point scale (abs err 1/32)

__device__ __forceinline__ u16 f2bf(float f) {
  unsigned int u = __float_as_uint(f);
  u = (u + 0x7FFFu + ((u >> 16) & 1u)) >> 16;  // round-to-nearest-even
  return (u16)u;
}
__device__ __forceinline__ float bf2f(u16 h) {
  return __uint_as_float(((unsigned int)h) << 16);
}
__device__ __forceinline__ signed char f2q8(float f) {
  float qf = fmaxf(-127.f, fminf(127.f, rintf(f * TSCALE)));
  return (signed char)(int)qf;
}

// =======================================================================
// Pass A: bucket edges into per-bucket record regions (packed 8B records)
// record = ((rl<<18 | col) << 32) | float_bits(val)
// =======================================================================

__global__ __launch_bounds__(256) void k_passA(const int* __restrict__ arow,
                                               const int* __restrict__ acol,
                                               const float* __restrict__ aval,
                                               int* __restrict__ bucketCur,
                                               unsigned long long* __restrict__ records) {
  __shared__ int cnt[NBUCK];
  __shared__ int base[NBUCK];
  int t = threadIdx.x;
  for (int i = t; i < NBUCK; i += 256) cnt[i] = 0;
  __syncthreads();
  int e0 = blockIdx.x * EPB;
  int e1 = e0 + EPB; if (e1 > N_EDGES) e1 = N_EDGES;
  for (int e = e0 + t; e < e1; e += 256) atomicAdd(&cnt[arow[e] >> 9], 1);
  __syncthreads();
  for (int i = t; i < NBUCK; i += 256) {
    int n = cnt[i];
    base[i] = n ? atomicAdd(&bucketCur[i], n) : 0;
    cnt[i] = 0;  // reuse as local cursor
  }
  __syncthreads();
  for (int e = e0 + t; e < e1; e += 256) {
    int r = arow[e];
    int b = r >> 9;
    int p = atomicAdd(&cnt[b], 1) + base[b];
    if (p < CAP) {
      unsigned int hi = ((unsigned int)(r & 511) << 18) | (unsigned int)acol[e];
      unsigned long long rec = ((unsigned long long)hi << 32) |
                               (unsigned int)__float_as_int(aval[e]);
      records[(size_t)b * CAP + p] = rec;
    }
  }
}

// =======================================================================
// Pass B: one WG per bucket -> exact compact CSR
// edge record: 4 bytes = (col:18 << 14) | q14(val); val = q * (1/16383)
// =======================================================================

__global__ __launch_bounds__(512) void k_passB(const int* __restrict__ bucketCur,
                                               const unsigned long long* __restrict__ records,
                                               int2* __restrict__ rowinfo,
                                               uint32* __restrict__ edges) {
  __shared__ int cnt[BROWS];
  __shared__ int sc[BROWS];
  __shared__ int cur[BROWS];
  int b = blockIdx.x;
  int t = threadIdx.x;
  int nrec = bucketCur[b]; if (nrec > CAP) nrec = CAP;
  const unsigned long long* rp = records + (size_t)b * CAP;
  cnt[t] = 0;
  __syncthreads();
  for (int i = t; i < nrec; i += 512) {
    unsigned int hi = (unsigned int)(rp[i] >> 32);
    atomicAdd(&cnt[hi >> 18], 1);
  }
  __syncthreads();
  sc[t] = cnt[t];
  __syncthreads();
  for (int d = 1; d < BROWS; d <<= 1) {
    int v = (t >= d) ? sc[t - d] : 0;
    __syncthreads();
    sc[t] += v;
    __syncthreads();
  }
  int pre = sc[t] - cnt[t];  // exclusive prefix
  cur[t] = pre;
  int r = b * BROWS + t;
  if (r < N_NODES) rowinfo[r] = make_int2(b * CAP + pre, cnt[t]);
  __syncthreads();
  for (int i = t; i < nrec; i += 512) {
    unsigned long long rec = rp[i];
    unsigned int hi = (unsigned int)(rec >> 32);
    int rl = hi >> 18;
    unsigned int col = hi & 0x3FFFFu;
    float val = __int_as_float((int)(unsigned int)rec);
    int q = (int)fmaf(val, 16383.f, 0.5f);
    q = q < 0 ? 0 : (q > 16383 ? 16383 : q);
    int p = atomicAdd(&cur[rl], 1);
    edges[(size_t)b * CAP + p] = (col << 14) | (unsigned int)q;
  }
}

// =======================================================================
// x transpose: x [node][128] fp32 -> xT [kp][node] u32 (bf16 pair k=2kp,2kp+1)
// One-shot blocks (64-node x 128-k tile, one barrier) — coalesced both sides.
// 200000 = 64 * 3125 exactly, no tail.
// =======================================================================

__global__ __launch_bounds__(256) void k_xpose(const float* __restrict__ x,
                                               uint32* __restrict__ xT) {
  __shared__ u16 tile[64 * 136];   // [row][k], stride 136 to spread banks
  int t = threadIdx.x;
  const float4* x4 = (const float4*)x;
  size_t base4 = (size_t)blockIdx.x * 2048;   // 64 rows * 32 float4
#pragma unroll
  for (int j = 0; j < 8; j++) {
    float4 v = x4[base4 + t + 256 * j];
    int row = (t >> 5) + 8 * j;
    int k0 = (t & 31) * 4;
    ushort4 p;
    p.x = f2bf(v.x); p.y = f2bf(v.y); p.z = f2bf(v.z); p.w = f2bf(v.w);
    *(ushort4*)&tile[row * 136 + k0] = p;
  }
  __syncthreads();
  int kp = t & 63;   // k-pair index 0..63
  int nq = t >> 6;   // node quarter 0..3
  uint32 o[16];
#pragma unroll
  for (int r = 0; r < 16; r++) {
    int node = nq * 16 + r;
    o[r] = *(const uint32*)&tile[node * 136 + kp * 2];  // {k=2kp (lo), 2kp+1 (hi)}
  }
  uint32* dst = xT + (size_t)kp * N_NODES + blockIdx.x * 64 + nq * 16;
#pragma unroll
  for (int r = 0; r < 16; r += 4) {
    *(uint4*)(dst + r) = make_uint4(o[r], o[r + 1], o[r + 2], o[r + 3]);
  }
}

// =======================================================================
// dense layer 1 on transposed x: t = x@W1 (int8 out), s = x@W2 (bf16 out)
// Thread-per-node; per instruction the wave reads 64 consecutive u32 =
// 256B fully coalesced. 8-deep staged loads; 1024 FMAs per stage hide
// latency. Weights stay on the scalar path (k, base wave-uniform).
// =======================================================================

__global__ __launch_bounds__(256) void k_dense1(const uint32* __restrict__ xT,
                                                const float* __restrict__ W1,
                                                const float* __restrict__ W2,
                                                signed char* __restrict__ tout,
                                                u16* __restrict__ sout) {
  int node = blockIdx.x * blockDim.x + threadIdx.x;
  if (node >= N_NODES) return;
  float acc1[CH], acc2[CH];
#pragma unroll
  for (int c = 0; c < CH; c++) { acc1[c] = 0.f; acc2[c] = 0.f; }
  for (int kp0 = 0; kp0 < 64; kp0 += 8) {
    uint32 st[8];
#pragma unroll
    for (int i = 0; i < 8; i++) st[i] = xT[(size_t)(kp0 + i) * N_NODES + node];
#pragma unroll
    for (int i = 0; i < 8; i++) {
      float xlo = bf2f((u16)(st[i] & 0xffffu));
      float xhi = bf2f((u16)(st[i] >> 16));
      const float* w1lo = W1 + (size_t)(2 * (kp0 + i)) * CH;
      const float* w2lo = W2 + (size_t)(2 * (kp0 + i)) * CH;
#pragma unroll
      for (int c = 0; c < CH; c++) {
        acc1[c] = fmaf(xlo, w1lo[c], acc1[c]);
        acc2[c] = fmaf(xlo, w2lo[c], acc2[c]);
      }
#pragma unroll
      for (int c = 0; c < CH; c++) {
        acc1[c] = fmaf(xhi, w1lo[CH + c], acc1[c]);
        acc2[c] = fmaf(xhi, w2lo[CH + c], acc2[c]);
      }
    }
  }
  uint32* tp = (uint32*)(tout + (size_t)node * CH);
#pragma unroll
  for (int c = 0; c < CH; c += 4) {
    uint32 p = ((uint32)(unsigned char)f2q8(acc1[c])) |
               ((uint32)(unsigned char)f2q8(acc1[c + 1]) << 8) |
               ((uint32)(unsigned char)f2q8(acc1[c + 2]) << 16) |
               ((uint32)(unsigned char)f2q8(acc1[c + 3]) << 24);
    tp[c >> 2] = p;
  }
  uint32* sp = (uint32*)(sout + (size_t)node * CH);
#pragma unroll
  for (int c = 0; c < CH; c += 2) {
    sp[c >> 1] = (uint32)f2bf(acc2[c]) | ((uint32)f2bf(acc2[c + 1]) << 16);
  }
}

// =======================================================================
// Fused: agg = SpMM(t_int8) ; h = relu(agg + s + b) ; [t',s'] = h @ [W1n,W2n]
// 8-way software-pipelined edge loop; int8 gather rows (32B, 2 nodes/line);
// 4B edge records (14-bit fixed val); both scales folded out of the loop.
// =======================================================================

template <int MODE>
__global__ __launch_bounds__(256) void k_gcs(const int2* __restrict__ rowinfo,
                                             const uint32* __restrict__ edges,
                                             const signed char* __restrict__ tin,
                                             u16* __restrict__ sio,
                                             const float* __restrict__ bias,
                                             const float* __restrict__ W1n,
                                             const float* __restrict__ W2n,
                                             signed char* __restrict__ tout,
                                             float* __restrict__ hout) {
  int gid = blockIdx.x * blockDim.x + threadIdx.x;
  int node = gid >> 5;
  int c = gid & 31;
  if (node >= N_NODES) return;
  int2 ri = rowinfo[node];
  const uint32* ep = edges + ri.x;
  int n = ri.y;
  float s = bf2f(sio[((size_t)node << 5) + c]);  // hoisted
  float a0 = 0.f, a1 = 0.f, a2 = 0.f, a3 = 0.f;
  for (int e = 0; e < n; e += 8) {
    int i0 = e + 0, i1 = e + 1, i2 = e + 2, i3 = e + 3;
    int i4 = e + 4, i5 = e + 5, i6 = e + 6, i7 = e + 7;
    uint32 d0 = ep[i0 < n ? i0 : n - 1];
    uint32 d1 = ep[i1 < n ? i1 : n - 1];
    uint32 d2 = ep[i2 < n ? i2 : n - 1];
    uint32 d3 = ep[i3 < n ? i3 : n - 1];
    uint32 d4 = ep[i4 < n ? i4 : n - 1];
    uint32 d5 = ep[i5 < n ? i5 : n - 1];
    uint32 d6 = ep[i6 < n ? i6 : n - 1];
    uint32 d7 = ep[i7 < n ? i7 : n - 1];
    int g0 = (int)tin[((size_t)(d0 >> 14) << 5) + c];
    int g1 = (int)tin[((size_t)(d1 >> 14) << 5) + c];
    int g2 = (int)tin[((size_t)(d2 >> 14) << 5) + c];
    int g3 = (int)tin[((size_t)(d3 >> 14) << 5) + c];
    int g4 = (int)tin[((size_t)(d4 >> 14) << 5) + c];
    int g5 = (int)tin[((size_t)(d5 >> 14) << 5) + c];
    int g6 = (int)tin[((size_t)(d6 >> 14) << 5) + c];
    int g7 = (int)tin[((size_t)(d7 >> 14) << 5) + c];
    float v0 = (i0 < n) ? (float)(d0 & 0x3FFFu) : 0.f;
    float v1 = (i1 < n) ? (float)(d1 & 0x3FFFu) : 0.f;
    float v2 = (i2 < n) ? (float)(d2 & 0x3FFFu) : 0.f;
    float v3 = (i3 < n) ? (float)(d3 & 0x3FFFu) : 0.f;
    float v4 = (i4 < n) ? (float)(d4 & 0x3FFFu) : 0.f;
    float v5 = (i5 < n) ? (float)(d5 & 0x3FFFu) : 0.f;
    float v6 = (i6 < n) ? (float)(d6 & 0x3FFFu) : 0.f;
    float v7 = (i7 < n) ? (float)(d7 & 0x3FFFu) : 0.f;
    a0 = fmaf(v0, (float)g0, a0);
    a1 = fmaf(v1, (float)g1, a1);
    a2 = fmaf(v2, (float)g2, a2);
    a3 = fmaf(v3, (float)g3, a3);
    a0 = fmaf(v4, (float)g4, a0);
    a1 = fmaf(v5, (float)g5, a1);
    a2 = fmaf(v6, (float)g6, a2);
    a3 = fmaf(v7, (float)g7, a3);
  }
  float acc = ((a0 + a1) + (a2 + a3)) * (1.f / (16383.f * TSCALE));
  float h = fmaxf(acc + s + bias[c], 0.f);
  if (MODE == 1) {
    hout[((size_t)node << 5) + c] = h;
  } else {
    float m1 = 0.f, m2 = 0.f;
#pragma unroll
    for (int k = 0; k < CH; k++) {
      float hk = __shfl(h, k, 32);
      m1 = fmaf(hk, W1n[k * CH + c], m1);
      m2 = fmaf(hk, W2n[k * CH + c], m2);
    }
    tout[((size_t)node << 5) + c] = f2q8(m1);   // 64 consecutive bytes per wave
    sio[((size_t)node << 5) + c] = f2bf(m2);    // in-place: read happened above
  }
}

// =======================================================================
// pool (segment mean via binary search) + dense + softmax
// =======================================================================

__global__ void k_head(const float* __restrict__ h, const int* __restrict__ seg,
                       const float* __restrict__ Wd, const float* __restrict__ bd,
                       float* __restrict__ out) {
  int g = blockIdx.x;
  int t = threadIdx.x;
  __shared__ float red[64];
  __shared__ float pooled[CH];
  __shared__ float logits[N_LABELS];
  int lo, hi;
  {
    int l = 0, r = N_NODES;
    while (l < r) { int m = (l + r) >> 1; if (seg[m] < g) l = m + 1; else r = m; }
    lo = l;
  }
  {
    int l = 0, r = N_NODES;
    while (l < r) { int m = (l + r) >> 1; if (seg[m] < g + 1) l = m + 1; else r = m; }
    hi = l;
  }
  float acc = 0.f;
  int c = t & 31, half = t >> 5;
  for (int i = lo + half; i < hi; i += 2) acc += h[(size_t)i * CH + c];
  red[t] = acc;
  __syncthreads();
  if (t < CH) {
    float cnt = (float)((hi - lo) > 0 ? (hi - lo) : 1);
    pooled[t] = (red[t] + red[t + 32]) / cnt;
  }
  __syncthreads();
  if (t < N_LABELS) {
    float a = bd[t];
#pragma unroll
    for (int k = 0; k < CH; k++) a = fmaf(pooled[k], Wd[k * N_LABELS + t], a);
    logits[t] = a;
  }
  __syncthreads();
  if (t == 0) {
    float mx = logits[0];
    for (int j = 1; j < N_LABELS; j++) mx = fmaxf(mx, logits[j]);
    float ssum = 0.f;
    float e[N_LABELS];
    for (int j = 0; j < N_LABELS; j++) { e[j] = expf(logits[j] - mx); ssum += e[j]; }
    float inv = 1.f / ssum;
    for (int j = 0; j < N_LABELS; j++) out[(size_t)g * N_LABELS + j] = e[j] * inv;
  }
}

// =======================================================================
// launch
// =======================================================================

extern "C" void kernel_launch(void* const* d_in, const int* in_sizes, int n_in,
                              void* d_out, int out_size, void* d_ws, size_t ws_size,
                              hipStream_t stream) {
  const float* x    = (const float*)d_in[0];
  const int*   arow = (const int*)d_in[1];
  const int*   acol = (const int*)d_in[2];
  const float* aval = (const float*)d_in[3];
  const int*   seg  = (const int*)d_in[4];
  const float* W1_1 = (const float*)d_in[5];
  const float* W2_1 = (const float*)d_in[6];
  const float* b_1  = (const float*)d_in[7];
  const float* W1_2 = (const float*)d_in[8];
  const float* W2_2 = (const float*)d_in[9];
  const float* b_2  = (const float*)d_in[10];
  const float* W1_3 = (const float*)d_in[11];
  const float* W2_3 = (const float*)d_in[12];
  const float* b_3  = (const float*)d_in[13];
  const float* Wd   = (const float*)d_in[14];
  const float* bd   = (const float*)d_in[15];
  float* out = (float*)d_out;

  char* w = (char*)d_ws;
  signed char* tA = (signed char*)w; w += (size_t)N_NODES * CH;      // 6.4 MB
  signed char* tB = (signed char*)w; w += (size_t)N_NODES * CH;      // 6.4 MB
  u16* sS = (u16*)w;                 w += (size_t)N_NODES * CH * 2;  // 12.8 MB
  float* hbuf = (float*)w;           w += (size_t)N_NODES * CH * 4;  // 25.6 MB
  uint32* edges = (uint32*)w;        w += (size_t)NBUCK * CAP * 4;   // 16.0 MB
  int2* rowinfo = (int2*)w;          w += (size_t)N_NODES * 8;       // 1.6 MB
  int* bucketCur = (int*)w;          w += 4096;
  uint32* xT = (uint32*)w;           w += (size_t)64 * N_NODES * 4;  // 51.2 MB
  // records (32 MB) aliases [tA|tB|sS|hbuf] (51.2 MB): dead before k_dense1
  unsigned long long* records = (unsigned long long*)d_ws;

  // ---- build exact compact CSR ----
  hipMemsetAsync(bucketCur, 0, (size_t)NBUCK * 4, stream);
  k_passA<<<(N_EDGES + EPB - 1) / EPB, 256, 0, stream>>>(arow, acol, aval, bucketCur, records);
  k_passB<<<NBUCK, 512, 0, stream>>>(bucketCur, records, rowinfo, edges);

  // ---- transpose x (fp32 [node][k] -> bf16-pair [k/2][node]) ----
  k_xpose<<<N_NODES / 64, 256, 0, stream>>>(x, xT);

  // ---- layer 1 dense projections (project BEFORE aggregation: 128 -> 32) ----
  k_dense1<<<(N_NODES + 255) / 256, 256, 0, stream>>>(xT, W1_1, W2_1, tA, sS);

  const int GCS_GRID = (N_NODES * 32 + 255) / 256;
  // layer 1 (+ layer-2 dense), layer 2 (+ layer-3 dense), layer 3 (combine only)
  k_gcs<0><<<GCS_GRID, 256, 0, stream>>>(rowinfo, edges, tA, sS, b_1, W1_2, W2_2, tB, nullptr);
  k_gcs<0><<<GCS_GRID, 256, 0, stream>>>(rowinfo, edges, tB, sS, b_2, W1_3, W2_3, tA, nullptr);
  k_gcs<1><<<GCS_GRID, 256, 0, stream>>>(rowinfo, edges, tA, sS, b_3, nullptr, nullptr, nullptr, hbuf);

  // ---- pool + head + softmax ----
  k_head<<<N_GRAPHS, 64, 0, stream>>>(hbuf, seg, Wd, bd, out);
}

// Round 11
// 457.953 us; speedup vs baseline: 1.0191x; 1.0191x over previous
//
#include <hip/hip_runtime.h>
#include <cstdint>

#define N_NODES 200000
#define N_EDGES 3200000
#define F_IN 128
#define CH 32
#define N_GRAPHS 1024
#define N_LABELS 17

#define BROWS 512                 // rows per bucket
#define NBUCK ((N_NODES + BROWS - 1) / BROWS)   // 391
#define CAP 10240                 // record capacity per bucket (mean 8192, sd ~90)
#define EPB 8192                  // edges per workgroup in pass A

typedef unsigned int uint32;
typedef unsigned short u16;

#define TSCALE 16.f               // int8 t-table fixed-point scale (abs err 1/32)

__device__ __forceinline__ u16 f2bf(float f) {
  unsigned int u = __float_as_uint(f);
  u = (u + 0x7FFFu + ((u >> 16) & 1u)) >> 16;  // round-to-nearest-even
  return (u16)u;
}
__device__ __forceinline__ float bf2f(u16 h) {
  return __uint_as_float(((unsigned int)h) << 16);
}
__device__ __forceinline__ signed char f2q8(float f) {
  float qf = fmaxf(-127.f, fminf(127.f, rintf(f * TSCALE)));
  return (signed char)(int)qf;
}

// =======================================================================
// Pass A: bucket edges into per-bucket record regions (packed 8B records)
// =======================================================================

__global__ __launch_bounds__(256) void k_passA(const int* __restrict__ arow,
                                               const int* __restrict__ acol,
                                               const float* __restrict__ aval,
                                               int* __restrict__ bucketCur,
                                               unsigned long long* __restrict__ records) {
  __shared__ int cnt[NBUCK];
  __shared__ int base[NBUCK];
  int t = threadIdx.x;
  for (int i = t; i < NBUCK; i += 256) cnt[i] = 0;
  __syncthreads();
  int e0 = blockIdx.x * EPB;
  int e1 = e0 + EPB; if (e1 > N_EDGES) e1 = N_EDGES;
  for (int e = e0 + t; e < e1; e += 256) atomicAdd(&cnt[arow[e] >> 9], 1);
  __syncthreads();
  for (int i = t; i < NBUCK; i += 256) {
    int n = cnt[i];
    base[i] = n ? atomicAdd(&bucketCur[i], n) : 0;
    cnt[i] = 0;  // reuse as local cursor
  }
  __syncthreads();
  for (int e = e0 + t; e < e1; e += 256) {
    int r = arow[e];
    int b = r >> 9;
    int p = atomicAdd(&cnt[b], 1) + base[b];
    if (p < CAP) {
      unsigned int hi = ((unsigned int)(r & 511) << 18) | (unsigned int)acol[e];
      unsigned long long rec = ((unsigned long long)hi << 32) |
                               (unsigned int)__float_as_int(aval[e]);
      records[(size_t)b * CAP + p] = rec;
    }
  }
}

// =======================================================================
// Pass B: one WG per bucket -> exact compact CSR
// edge record: 4 bytes = (col:18 << 14) | q14(val); val = q * (1/16383)
// =======================================================================

__global__ __launch_bounds__(512) void k_passB(const int* __restrict__ bucketCur,
                                               const unsigned long long* __restrict__ records,
                                               int2* __restrict__ rowinfo,
                                               uint32* __restrict__ edges) {
  __shared__ int cnt[BROWS];
  __shared__ int sc[BROWS];
  __shared__ int cur[BROWS];
  int b = blockIdx.x;
  int t = threadIdx.x;
  int nrec = bucketCur[b]; if (nrec > CAP) nrec = CAP;
  const unsigned long long* rp = records + (size_t)b * CAP;
  cnt[t] = 0;
  __syncthreads();
  for (int i = t; i < nrec; i += 512) {
    unsigned int hi = (unsigned int)(rp[i] >> 32);
    atomicAdd(&cnt[hi >> 18], 1);
  }
  __syncthreads();
  sc[t] = cnt[t];
  __syncthreads();
  for (int d = 1; d < BROWS; d <<= 1) {
    int v = (t >= d) ? sc[t - d] : 0;
    __syncthreads();
    sc[t] += v;
    __syncthreads();
  }
  int pre = sc[t] - cnt[t];  // exclusive prefix
  cur[t] = pre;
  int r = b * BROWS + t;
  if (r < N_NODES) rowinfo[r] = make_int2(b * CAP + pre, cnt[t]);
  __syncthreads();
  for (int i = t; i < nrec; i += 512) {
    unsigned long long rec = rp[i];
    unsigned int hi = (unsigned int)(rec >> 32);
    int rl = hi >> 18;
    unsigned int col = hi & 0x3FFFFu;
    float val = __int_as_float((int)(unsigned int)rec);
    int q = (int)fmaf(val, 16383.f, 0.5f);
    q = q < 0 ? 0 : (q > 16383 ? 16383 : q);
    int p = atomicAdd(&cur[rl], 1);
    edges[(size_t)b * CAP + p] = (col << 14) | (unsigned int)q;
  }
}

// =======================================================================
// dense layer 1: t = x@W1 (int8, split halves), s = x@W2 (bf16)
// Proven r9 structure: thread-per-node, scalar weight path, unroll 8.
// =======================================================================

__global__ __launch_bounds__(256) void k_dense1(const float* __restrict__ x,
                                                const float* __restrict__ W1,
                                                const float* __restrict__ W2,
                                                signed char* __restrict__ tlo,
                                                signed char* __restrict__ thi,
                                                u16* __restrict__ sout) {
  int i = blockIdx.x * blockDim.x + threadIdx.x;
  if (i >= N_NODES) return;
  const float* xr = x + (size_t)i * F_IN;
  float acc1[CH], acc2[CH];
#pragma unroll
  for (int c = 0; c < CH; c++) { acc1[c] = 0.f; acc2[c] = 0.f; }
#pragma unroll 8
  for (int k = 0; k < F_IN; k += 4) {
    float4 xv = *(const float4*)(xr + k);
    float xk[4] = {xv.x, xv.y, xv.z, xv.w};
#pragma unroll
    for (int kk = 0; kk < 4; kk++) {
      float xval = xk[kk];
      const float* w1r = W1 + (size_t)(k + kk) * CH;
      const float* w2r = W2 + (size_t)(k + kk) * CH;
#pragma unroll
      for (int c = 0; c < CH; c++) {
        acc1[c] = fmaf(xval, w1r[c], acc1[c]);
        acc2[c] = fmaf(xval, w2r[c], acc2[c]);
      }
    }
  }
  uint32* tlp = (uint32*)(tlo + ((size_t)i << 4));
  uint32* thp = (uint32*)(thi + ((size_t)i << 4));
#pragma unroll
  for (int c = 0; c < 16; c += 4) {
    tlp[c >> 2] = ((uint32)(unsigned char)f2q8(acc1[c])) |
                  ((uint32)(unsigned char)f2q8(acc1[c + 1]) << 8) |
                  ((uint32)(unsigned char)f2q8(acc1[c + 2]) << 16) |
                  ((uint32)(unsigned char)f2q8(acc1[c + 3]) << 24);
    thp[c >> 2] = ((uint32)(unsigned char)f2q8(acc1[16 + c])) |
                  ((uint32)(unsigned char)f2q8(acc1[16 + c + 1]) << 8) |
                  ((uint32)(unsigned char)f2q8(acc1[16 + c + 2]) << 16) |
                  ((uint32)(unsigned char)f2q8(acc1[16 + c + 3]) << 24);
  }
  uint32* sp = (uint32*)(sout + ((size_t)i << 5));
#pragma unroll
  for (int c = 0; c < CH; c += 2) {
    sp[c >> 1] = (uint32)f2bf(acc2[c]) | ((uint32)f2bf(acc2[c + 1]) << 16);
  }
}

// =======================================================================
// Half-channel gather: agg = SpMM(t_half) ; h_half = relu(agg + s + b)
// Table half = 3.2MB -> fits per-XCD L2 (4MB): all gathers L2-hit.
// Quarter-wave (16 lanes) per node; 8-deep edge pipeline -> 32 gathers
// in flight per wave. choff selects s/bias channel window.
// =======================================================================

__global__ __launch_bounds__(256) void k_gcsh(const int2* __restrict__ rowinfo,
                                              const uint32* __restrict__ edges,
                                              const signed char* __restrict__ tin,
                                              const u16* __restrict__ sio,
                                              const float* __restrict__ bias,
                                              u16* __restrict__ hout, int choff) {
  int gid = blockIdx.x * blockDim.x + threadIdx.x;
  int node = gid >> 4;
  int c = gid & 15;
  if (node >= N_NODES) return;
  int2 ri = rowinfo[node];
  const uint32* ep = edges + ri.x;
  int n = ri.y;
  float s = bf2f(sio[((size_t)node << 5) + choff + c]);  // hoisted
  float a0 = 0.f, a1 = 0.f, a2 = 0.f, a3 = 0.f;
  for (int e = 0; e < n; e += 8) {
    int i0 = e + 0, i1 = e + 1, i2 = e + 2, i3 = e + 3;
    int i4 = e + 4, i5 = e + 5, i6 = e + 6, i7 = e + 7;
    uint32 d0 = ep[i0 < n ? i0 : n - 1];
    uint32 d1 = ep[i1 < n ? i1 : n - 1];
    uint32 d2 = ep[i2 < n ? i2 : n - 1];
    uint32 d3 = ep[i3 < n ? i3 : n - 1];
    uint32 d4 = ep[i4 < n ? i4 : n - 1];
    uint32 d5 = ep[i5 < n ? i5 : n - 1];
    uint32 d6 = ep[i6 < n ? i6 : n - 1];
    uint32 d7 = ep[i7 < n ? i7 : n - 1];
    int g0 = (int)tin[((size_t)(d0 >> 14) << 4) + c];
    int g1 = (int)tin[((size_t)(d1 >> 14) << 4) + c];
    int g2 = (int)tin[((size_t)(d2 >> 14) << 4) + c];
    int g3 = (int)tin[((size_t)(d3 >> 14) << 4) + c];
    int g4 = (int)tin[((size_t)(d4 >> 14) << 4) + c];
    int g5 = (int)tin[((size_t)(d5 >> 14) << 4) + c];
    int g6 = (int)tin[((size_t)(d6 >> 14) << 4) + c];
    int g7 = (int)tin[((size_t)(d7 >> 14) << 4) + c];
    float v0 = (i0 < n) ? (float)(d0 & 0x3FFFu) : 0.f;
    float v1 = (i1 < n) ? (float)(d1 & 0x3FFFu) : 0.f;
    float v2 = (i2 < n) ? (float)(d2 & 0x3FFFu) : 0.f;
    float v3 = (i3 < n) ? (float)(d3 & 0x3FFFu) : 0.f;
    float v4 = (i4 < n) ? (float)(d4 & 0x3FFFu) : 0.f;
    float v5 = (i5 < n) ? (float)(d5 & 0x3FFFu) : 0.f;
    float v6 = (i6 < n) ? (float)(d6 & 0x3FFFu) : 0.f;
    float v7 = (i7 < n) ? (float)(d7 & 0x3FFFu) : 0.f;
    a0 = fmaf(v0, (float)g0, a0);
    a1 = fmaf(v1, (float)g1, a1);
    a2 = fmaf(v2, (float)g2, a2);
    a3 = fmaf(v3, (float)g3, a3);
    a0 = fmaf(v4, (float)g4, a0);
    a1 = fmaf(v5, (float)g5, a1);
    a2 = fmaf(v6, (float)g6, a2);
    a3 = fmaf(v7, (float)g7, a3);
  }
  float acc = ((a0 + a1) + (a2 + a3)) * (1.f / (16383.f * TSCALE));
  float h = fmaxf(acc + s + bias[choff + c], 0.f);
  hout[((size_t)node << 4) + c] = f2bf(h);
}

// =======================================================================
// Mix: h (bf16 halves) -> t' = q8(h@W1n) halves, s' = bf16(h@W2n)
// Wave = 2 nodes, lane c = 0..31; 32x32 matmul via shfl; scalar weights.
// =======================================================================

__global__ __launch_bounds__(256) void k_mix(const u16* __restrict__ hl,
                                             const u16* __restrict__ hh,
                                             const float* __restrict__ W1n,
                                             const float* __restrict__ W2n,
                                             signed char* __restrict__ tlo,
                                             signed char* __restrict__ thi,
                                             u16* __restrict__ sio) {
  int gid = blockIdx.x * blockDim.x + threadIdx.x;
  int node = gid >> 5;
  int c = gid & 31;
  if (node >= N_NODES) return;
  const u16* hp = (c < 16) ? hl : hh;
  float h = bf2f(hp[((size_t)node << 4) + (c & 15)]);
  float m1 = 0.f, m2 = 0.f;
#pragma unroll
  for (int k = 0; k < CH; k++) {
    float hk = __shfl(h, k, 32);
    m1 = fmaf(hk, W1n[k * CH + c], m1);
    m2 = fmaf(hk, W2n[k * CH + c], m2);
  }
  signed char* tp = (c < 16) ? tlo : thi;
  tp[((size_t)node << 4) + (c & 15)] = f2q8(m1);
  sio[((size_t)node << 5) + c] = f2bf(m2);
}

// =======================================================================
// pool (segment mean via binary search) + dense + softmax (h in bf16 halves)
// =======================================================================

__global__ void k_head(const u16* __restrict__ hl, const u16* __restrict__ hh,
                       const int* __restrict__ seg, const float* __restrict__ Wd,
                       const float* __restrict__ bd, float* __restrict__ out) {
  int g = blockIdx.x;
  int t = threadIdx.x;
  __shared__ float red[64];
  __shared__ float pooled[CH];
  __shared__ float logits[N_LABELS];
  int lo, hi;
  {
    int l = 0, r = N_NODES;
    while (l < r) { int m = (l + r) >> 1; if (seg[m] < g) l = m + 1; else r = m; }
    lo = l;
  }
  {
    int l = 0, r = N_NODES;
    while (l < r) { int m = (l + r) >> 1; if (seg[m] < g + 1) l = m + 1; else r = m; }
    hi = l;
  }
  float acc = 0.f;
  int c = t & 31, half = t >> 5;
  const u16* hp = (c < 16) ? hl : hh;
  int ci = c & 15;
  for (int i = lo + half; i < hi; i += 2) acc += bf2f(hp[((size_t)i << 4) + ci]);
  red[t] = acc;
  __syncthreads();
  if (t < CH) {
    float cnt = (float)((hi - lo) > 0 ? (hi - lo) : 1);
    pooled[t] = (red[t] + red[t + 32]) / cnt;
  }
  __syncthreads();
  if (t < N_LABELS) {
    float a = bd[t];
#pragma unroll
    for (int k = 0; k < CH; k++) a = fmaf(pooled[k], Wd[k * N_LABELS + t], a);
    logits[t] = a;
  }
  __syncthreads();
  if (t == 0) {
    float mx = logits[0];
    for (int j = 1; j < N_LABELS; j++) mx = fmaxf(mx, logits[j]);
    float ssum = 0.f;
    float e[N_LABELS];
    for (int j = 0; j < N_LABELS; j++) { e[j] = expf(logits[j] - mx); ssum += e[j]; }
    float inv = 1.f / ssum;
    for (int j = 0; j < N_LABELS; j++) out[(size_t)g * N_LABELS + j] = e[j] * inv;
  }
}

// =======================================================================
// launch
// =======================================================================

extern "C" void kernel_launch(void* const* d_in, const int* in_sizes, int n_in,
                              void* d_out, int out_size, void* d_ws, size_t ws_size,
                              hipStream_t stream) {
  const float* x    = (const float*)d_in[0];
  const int*   arow = (const int*)d_in[1];
  const int*   acol = (const int*)d_in[2];
  const float* aval = (const float*)d_in[3];
  const int*   seg  = (const int*)d_in[4];
  const float* W1_1 = (const float*)d_in[5];
  const float* W2_1 = (const float*)d_in[6];
  const float* b_1  = (const float*)d_in[7];
  const float* W1_2 = (const float*)d_in[8];
  const float* W2_2 = (const float*)d_in[9];
  const float* b_2  = (const float*)d_in[10];
  const float* W1_3 = (const float*)d_in[11];
  const float* W2_3 = (const float*)d_in[12];
  const float* b_3  = (const float*)d_in[13];
  const float* Wd   = (const float*)d_in[14];
  const float* bd   = (const float*)d_in[15];
  float* out = (float*)d_out;

  const size_t HALF = (size_t)N_NODES * 16;   // 3.2 MB (int8) / 6.4 MB (u16)

  char* w = (char*)d_ws;
  signed char* tAlo = (signed char*)w; w += HALF;          // 3.2 MB
  signed char* tAhi = (signed char*)w; w += HALF;          // 3.2 MB
  signed char* tBlo = (signed char*)w; w += HALF;          // 3.2 MB
  signed char* tBhi = (signed char*)w; w += HALF;          // 3.2 MB
  u16* sS = (u16*)w;                   w += (size_t)N_NODES * CH * 2;  // 12.8 MB
  u16* hL = (u16*)w;                   w += HALF * 2;      // 6.4 MB
  u16* hH = (u16*)w;                   w += HALF * 2;      // 6.4 MB
  // --- records (32.1 MB) aliases [tAlo..hH] (41.6 MB): dead before k_dense1
  uint32* edges = (uint32*)w;          w += (size_t)NBUCK * CAP * 4;   // 16.0 MB
  int2* rowinfo = (int2*)w;            w += (size_t)N_NODES * 8;       // 1.6 MB
  int* bucketCur = (int*)w;            w += 4096;
  unsigned long long* records = (unsigned long long*)d_ws;

  // ---- build exact compact CSR ----
  hipMemsetAsync(bucketCur, 0, (size_t)NBUCK * 4, stream);
  k_passA<<<(N_EDGES + EPB - 1) / EPB, 256, 0, stream>>>(arow, acol, aval, bucketCur, records);
  k_passB<<<NBUCK, 512, 0, stream>>>(bucketCur, records, rowinfo, edges);

  // ---- layer 1 dense projections (project BEFORE aggregation: 128 -> 32) ----
  k_dense1<<<(N_NODES + 255) / 256, 256, 0, stream>>>(x, W1_1, W2_1, tAlo, tAhi, sS);

  const int GH_GRID = (N_NODES * 16 + 255) / 256;   // 12500
  const int MIX_GRID = (N_NODES * 32 + 255) / 256;  // 25000

  // layer 1
  k_gcsh<<<GH_GRID, 256, 0, stream>>>(rowinfo, edges, tAlo, sS, b_1, hL, 0);
  k_gcsh<<<GH_GRID, 256, 0, stream>>>(rowinfo, edges, tAhi, sS, b_1, hH, 16);
  k_mix<<<MIX_GRID, 256, 0, stream>>>(hL, hH, W1_2, W2_2, tBlo, tBhi, sS);
  // layer 2
  k_gcsh<<<GH_GRID, 256, 0, stream>>>(rowinfo, edges, tBlo, sS, b_2, hL, 0);
  k_gcsh<<<GH_GRID, 256, 0, stream>>>(rowinfo, edges, tBhi, sS, b_2, hH, 16);
  k_mix<<<MIX_GRID, 256, 0, stream>>>(hL, hH, W1_3, W2_3, tAlo, tAhi, sS);
  // layer 3 (no mix; head pools h directly)
  k_gcsh<<<GH_GRID, 256, 0, stream>>>(rowinfo, edges, tAlo, sS, b_3, hL, 0);
  k_gcsh<<<GH_GRID, 256, 0, stream>>>(rowinfo, edges, tAhi, sS, b_3, hH, 16);

  // ---- pool + head + softmax ----
  k_head<<<N_GRAPHS, 64, 0, stream>>>(hL, hH, seg, Wd, bd, out);
}

// Round 12
// 408.786 us; speedup vs baseline: 1.1416x; 1.1203x over previous
//
#include <hip/hip_runtime.h>
#include <cstdint>

#define N_NODES 200000
#define N_EDGES 3200000
#define F_IN 128
#define CH 32
#define N_GRAPHS 1024
#define N_LABELS 17

#define BROWS 512                 // rows per bucket
#define NBUCK ((N_NODES + BROWS - 1) / BROWS)   // 391
#define CAP 10240                 // record capacity per bucket (mean 8192, sd ~90)
#define EPB 8192                  // edges per workgroup in pass A

typedef unsigned int uint32;
typedef unsigned short u16;

#define TSCALE 16.f               // int8 t-table fixed-point scale (abs err 1/32)

__device__ __forceinline__ u16 f2bf(float f) {
  unsigned int u = __float_as_uint(f);
  u = (u + 0x7FFFu + ((u >> 16) & 1u)) >> 16;  // round-to-nearest-even
  return (u16)u;
}
__device__ __forceinline__ float bf2f(u16 h) {
  return __uint_as_float(((unsigned int)h) << 16);
}
__device__ __forceinline__ signed char f2q8(float f) {
  float qf = fmaxf(-127.f, fminf(127.f, rintf(f * TSCALE)));
  return (signed char)(int)qf;
}

// =======================================================================
// Pass A: bucket edges into per-bucket record regions (packed 8B records)
// record = ((rl<<18 | col) << 32) | float_bits(val)
// =======================================================================

__global__ __launch_bounds__(256) void k_passA(const int* __restrict__ arow,
                                               const int* __restrict__ acol,
                                               const float* __restrict__ aval,
                                               int* __restrict__ bucketCur,
                                               unsigned long long* __restrict__ records) {
  __shared__ int cnt[NBUCK];
  __shared__ int base[NBUCK];
  int t = threadIdx.x;
  for (int i = t; i < NBUCK; i += 256) cnt[i] = 0;
  __syncthreads();
  int e0 = blockIdx.x * EPB;
  int e1 = e0 + EPB; if (e1 > N_EDGES) e1 = N_EDGES;
  for (int e = e0 + t; e < e1; e += 256) atomicAdd(&cnt[arow[e] >> 9], 1);
  __syncthreads();
  for (int i = t; i < NBUCK; i += 256) {
    int n = cnt[i];
    base[i] = n ? atomicAdd(&bucketCur[i], n) : 0;
    cnt[i] = 0;  // reuse as local cursor
  }
  __syncthreads();
  for (int e = e0 + t; e < e1; e += 256) {
    int r = arow[e];
    int b = r >> 9;
    int p = atomicAdd(&cnt[b], 1) + base[b];
    if (p < CAP) {
      unsigned int hi = ((unsigned int)(r & 511) << 18) | (unsigned int)acol[e];
      unsigned long long rec = ((unsigned long long)hi << 32) |
                               (unsigned int)__float_as_int(aval[e]);
      records[(size_t)b * CAP + p] = rec;
    }
  }
}

// =======================================================================
// Pass B: one WG per bucket -> exact compact CSR
// edge record: 4 bytes = (col:18 << 14) | q14(val); val = q * (1/16383)
// =======================================================================

__global__ __launch_bounds__(512) void k_passB(const int* __restrict__ bucketCur,
                                               const unsigned long long* __restrict__ records,
                                               int2* __restrict__ rowinfo,
                                               uint32* __restrict__ edges) {
  __shared__ int cnt[BROWS];
  __shared__ int sc[BROWS];
  __shared__ int cur[BROWS];
  int b = blockIdx.x;
  int t = threadIdx.x;
  int nrec = bucketCur[b]; if (nrec > CAP) nrec = CAP;
  const unsigned long long* rp = records + (size_t)b * CAP;
  cnt[t] = 0;
  __syncthreads();
  for (int i = t; i < nrec; i += 512) {
    unsigned int hi = (unsigned int)(rp[i] >> 32);
    atomicAdd(&cnt[hi >> 18], 1);
  }
  __syncthreads();
  sc[t] = cnt[t];
  __syncthreads();
  for (int d = 1; d < BROWS; d <<= 1) {
    int v = (t >= d) ? sc[t - d] : 0;
    __syncthreads();
    sc[t] += v;
    __syncthreads();
  }
  int pre = sc[t] - cnt[t];  // exclusive prefix
  cur[t] = pre;
  int r = b * BROWS + t;
  if (r < N_NODES) rowinfo[r] = make_int2(b * CAP + pre, cnt[t]);
  __syncthreads();
  for (int i = t; i < nrec; i += 512) {
    unsigned long long rec = rp[i];
    unsigned int hi = (unsigned int)(rec >> 32);
    int rl = hi >> 18;
    unsigned int col = hi & 0x3FFFFu;
    float val = __int_as_float((int)(unsigned int)rec);
    int q = (int)fmaf(val, 16383.f, 0.5f);
    q = q < 0 ? 0 : (q > 16383 ? 16383 : q);
    int p = atomicAdd(&cur[rl], 1);
    edges[(size_t)b * CAP + p] = (col << 14) | (unsigned int)q;
  }
}

// =======================================================================
// dense layer 1: t = x@W1 (int8 out), s = x@W2 (bf16 out)
// r9 structure (thread-per-node, SGPR-uniform weight path) + explicit
// 2x8-float4 register ping-pong: 8 loads always in flight while 2048 FMAs
// retire (covers ~900cyc HBM latency). VGPR ~140 keeps 3 waves/SIMD =
// full residency for 782 blocks; L2 working set unchanged (r8 lesson).
// =======================================================================

__global__ __launch_bounds__(256) void k_dense1(const float* __restrict__ x,
                                                const float* __restrict__ W1,
                                                const float* __restrict__ W2,
                                                signed char* __restrict__ tout,
                                                u16* __restrict__ sout) {
  int i = blockIdx.x * blockDim.x + threadIdx.x;
  if (i >= N_NODES) return;
  const float4* xr = (const float4*)(x + (size_t)i * F_IN);   // 32 float4
  float acc1[CH], acc2[CH];
#pragma unroll
  for (int c = 0; c < CH; c++) { acc1[c] = 0.f; acc2[c] = 0.f; }
  float4 xa[8], xb[8];
#pragma unroll
  for (int j = 0; j < 8; j++) xa[j] = xr[j];        // group 0 in flight
#pragma unroll
  for (int j = 0; j < 8; j++) xb[j] = xr[8 + j];    // group 1 in flight
#pragma unroll
  for (int g = 0; g < 4; g++) {
    // compute on xa (k = g*32 .. g*32+31); prefetch group g+2 into xa after use
    const float* w1g = W1 + (size_t)g * 32 * CH;
    const float* w2g = W2 + (size_t)g * 32 * CH;
#pragma unroll
    for (int j = 0; j < 8; j++) {
      float xk[4] = {xa[j].x, xa[j].y, xa[j].z, xa[j].w};
      // refill this slot for group g+2 right after consuming it
      if (g < 2) xa[j] = xr[(g + 2) * 8 + j];
#pragma unroll
      for (int kk = 0; kk < 4; kk++) {
        float xval = xk[kk];
        const float* w1r = w1g + (j * 4 + kk) * CH;
        const float* w2r = w2g + (j * 4 + kk) * CH;
#pragma unroll
        for (int c = 0; c < CH; c++) {
          acc1[c] = fmaf(xval, w1r[c], acc1[c]);
          acc2[c] = fmaf(xval, w2r[c], acc2[c]);
        }
      }
    }
    // swap roles: xb becomes the compute group
#pragma unroll
    for (int j = 0; j < 8; j++) { float4 tmp = xa[j]; xa[j] = xb[j]; xb[j] = tmp; }
  }
  uint32* tp = (uint32*)(tout + (size_t)i * CH);
#pragma unroll
  for (int c = 0; c < CH; c += 4) {
    uint32 p = ((uint32)(unsigned char)f2q8(acc1[c])) |
               ((uint32)(unsigned char)f2q8(acc1[c + 1]) << 8) |
               ((uint32)(unsigned char)f2q8(acc1[c + 2]) << 16) |
               ((uint32)(unsigned char)f2q8(acc1[c + 3]) << 24);
    tp[c >> 2] = p;
  }
  uint32* sp = (uint32*)(sout + (size_t)i * CH);
#pragma unroll
  for (int c = 0; c < CH; c += 2) {
    sp[c >> 1] = (uint32)f2bf(acc2[c]) | ((uint32)f2bf(acc2[c + 1]) << 16);
  }
}

// =======================================================================
// Fused: agg = SpMM(t_int8) ; h = relu(agg + s + b) ; [t',s'] = h @ [W1n,W2n]
// 8-way software-pipelined edge loop; int8 gather rows (32B, 2 nodes/line);
// 4B edge records (14-bit fixed val); both scales folded out of the loop.
// =======================================================================

template <int MODE>
__global__ __launch_bounds__(256) void k_gcs(const int2* __restrict__ rowinfo,
                                             const uint32* __restrict__ edges,
                                             const signed char* __restrict__ tin,
                                             u16* __restrict__ sio,
                                             const float* __restrict__ bias,
                                             const float* __restrict__ W1n,
                                             const float* __restrict__ W2n,
                                             signed char* __restrict__ tout,
                                             float* __restrict__ hout) {
  int gid = blockIdx.x * blockDim.x + threadIdx.x;
  int node = gid >> 5;
  int c = gid & 31;
  if (node >= N_NODES) return;
  int2 ri = rowinfo[node];
  const uint32* ep = edges + ri.x;
  int n = ri.y;
  float s = bf2f(sio[((size_t)node << 5) + c]);  // hoisted
  float a0 = 0.f, a1 = 0.f, a2 = 0.f, a3 = 0.f;
  for (int e = 0; e < n; e += 8) {
    int i0 = e + 0, i1 = e + 1, i2 = e + 2, i3 = e + 3;
    int i4 = e + 4, i5 = e + 5, i6 = e + 6, i7 = e + 7;
    uint32 d0 = ep[i0 < n ? i0 : n - 1];
    uint32 d1 = ep[i1 < n ? i1 : n - 1];
    uint32 d2 = ep[i2 < n ? i2 : n - 1];
    uint32 d3 = ep[i3 < n ? i3 : n - 1];
    uint32 d4 = ep[i4 < n ? i4 : n - 1];
    uint32 d5 = ep[i5 < n ? i5 : n - 1];
    uint32 d6 = ep[i6 < n ? i6 : n - 1];
    uint32 d7 = ep[i7 < n ? i7 : n - 1];
    int g0 = (int)tin[((size_t)(d0 >> 14) << 5) + c];
    int g1 = (int)tin[((size_t)(d1 >> 14) << 5) + c];
    int g2 = (int)tin[((size_t)(d2 >> 14) << 5) + c];
    int g3 = (int)tin[((size_t)(d3 >> 14) << 5) + c];
    int g4 = (int)tin[((size_t)(d4 >> 14) << 5) + c];
    int g5 = (int)tin[((size_t)(d5 >> 14) << 5) + c];
    int g6 = (int)tin[((size_t)(d6 >> 14) << 5) + c];
    int g7 = (int)tin[((size_t)(d7 >> 14) << 5) + c];
    float v0 = (i0 < n) ? (float)(d0 & 0x3FFFu) : 0.f;
    float v1 = (i1 < n) ? (float)(d1 & 0x3FFFu) : 0.f;
    float v2 = (i2 < n) ? (float)(d2 & 0x3FFFu) : 0.f;
    float v3 = (i3 < n) ? (float)(d3 & 0x3FFFu) : 0.f;
    float v4 = (i4 < n) ? (float)(d4 & 0x3FFFu) : 0.f;
    float v5 = (i5 < n) ? (float)(d5 & 0x3FFFu) : 0.f;
    float v6 = (i6 < n) ? (float)(d6 & 0x3FFFu) : 0.f;
    float v7 = (i7 < n) ? (float)(d7 & 0x3FFFu) : 0.f;
    a0 = fmaf(v0, (float)g0, a0);
    a1 = fmaf(v1, (float)g1, a1);
    a2 = fmaf(v2, (float)g2, a2);
    a3 = fmaf(v3, (float)g3, a3);
    a0 = fmaf(v4, (float)g4, a0);
    a1 = fmaf(v5, (float)g5, a1);
    a2 = fmaf(v6, (float)g6, a2);
    a3 = fmaf(v7, (float)g7, a3);
  }
  float acc = ((a0 + a1) + (a2 + a3)) * (1.f / (16383.f * TSCALE));
  float h = fmaxf(acc + s + bias[c], 0.f);
  if (MODE == 1) {
    hout[((size_t)node << 5) + c] = h;
  } else {
    float m1 = 0.f, m2 = 0.f;
#pragma unroll
    for (int k = 0; k < CH; k++) {
      float hk = __shfl(h, k, 32);
      m1 = fmaf(hk, W1n[k * CH + c], m1);
      m2 = fmaf(hk, W2n[k * CH + c], m2);
    }
    tout[((size_t)node << 5) + c] = f2q8(m1);   // 64 consecutive bytes per wave
    sio[((size_t)node << 5) + c] = f2bf(m2);    // in-place: read happened above
  }
}

// =======================================================================
// pool (segment mean via binary search) + dense + softmax
// =======================================================================

__global__ void k_head(const float* __restrict__ h, const int* __restrict__ seg,
                       const float* __restrict__ Wd, const float* __restrict__ bd,
                       float* __restrict__ out) {
  int g = blockIdx.x;
  int t = threadIdx.x;
  __shared__ float red[64];
  __shared__ float pooled[CH];
  __shared__ float logits[N_LABELS];
  int lo, hi;
  {
    int l = 0, r = N_NODES;
    while (l < r) { int m = (l + r) >> 1; if (seg[m] < g) l = m + 1; else r = m; }
    lo = l;
  }
  {
    int l = 0, r = N_NODES;
    while (l < r) { int m = (l + r) >> 1; if (seg[m] < g + 1) l = m + 1; else r = m; }
    hi = l;
  }
  float acc = 0.f;
  int c = t & 31, half = t >> 5;
  for (int i = lo + half; i < hi; i += 2) acc += h[(size_t)i * CH + c];
  red[t] = acc;
  __syncthreads();
  if (t < CH) {
    float cnt = (float)((hi - lo) > 0 ? (hi - lo) : 1);
    pooled[t] = (red[t] + red[t + 32]) / cnt;
  }
  __syncthreads();
  if (t < N_LABELS) {
    float a = bd[t];
#pragma unroll
    for (int k = 0; k < CH; k++) a = fmaf(pooled[k], Wd[k * N_LABELS + t], a);
    logits[t] = a;
  }
  __syncthreads();
  if (t == 0) {
    float mx = logits[0];
    for (int j = 1; j < N_LABELS; j++) mx = fmaxf(mx, logits[j]);
    float ssum = 0.f;
    float e[N_LABELS];
    for (int j = 0; j < N_LABELS; j++) { e[j] = expf(logits[j] - mx); ssum += e[j]; }
    float inv = 1.f / ssum;
    for (int j = 0; j < N_LABELS; j++) out[(size_t)g * N_LABELS + j] = e[j] * inv;
  }
}

// =======================================================================
// launch
// =======================================================================

extern "C" void kernel_launch(void* const* d_in, const int* in_sizes, int n_in,
                              void* d_out, int out_size, void* d_ws, size_t ws_size,
                              hipStream_t stream) {
  const float* x    = (const float*)d_in[0];
  const int*   arow = (const int*)d_in[1];
  const int*   acol = (const int*)d_in[2];
  const float* aval = (const float*)d_in[3];
  const int*   seg  = (const int*)d_in[4];
  const float* W1_1 = (const float*)d_in[5];
  const float* W2_1 = (const float*)d_in[6];
  const float* b_1  = (const float*)d_in[7];
  const float* W1_2 = (const float*)d_in[8];
  const float* W2_2 = (const float*)d_in[9];
  const float* b_2  = (const float*)d_in[10];
  const float* W1_3 = (const float*)d_in[11];
  const float* W2_3 = (const float*)d_in[12];
  const float* b_3  = (const float*)d_in[13];
  const float* Wd   = (const float*)d_in[14];
  const float* bd   = (const float*)d_in[15];
  float* out = (float*)d_out;

  char* w = (char*)d_ws;
  signed char* tA = (signed char*)w; w += (size_t)N_NODES * CH;      // 6.4 MB
  signed char* tB = (signed char*)w; w += (size_t)N_NODES * CH;      // 6.4 MB
  u16* sS = (u16*)w;                 w += (size_t)N_NODES * CH * 2;  // 12.8 MB
  float* hbuf = (float*)w;           w += (size_t)N_NODES * CH * 4;  // 25.6 MB
  uint32* edges = (uint32*)w;        w += (size_t)NBUCK * CAP * 4;   // 16.0 MB
  int2* rowinfo = (int2*)w;          w += (size_t)N_NODES * 8;       // 1.6 MB
  int* bucketCur = (int*)w;          w += 4096;
  // records (32 MB) aliases [tA|tB|sS|hbuf] (51.2 MB): dead before k_dense1
  unsigned long long* records = (unsigned long long*)d_ws;

  // ---- build exact compact CSR ----
  hipMemsetAsync(bucketCur, 0, (size_t)NBUCK * 4, stream);
  k_passA<<<(N_EDGES + EPB - 1) / EPB, 256, 0, stream>>>(arow, acol, aval, bucketCur, records);
  k_passB<<<NBUCK, 512, 0, stream>>>(bucketCur, records, rowinfo, edges);

  // ---- layer 1 dense projections (project BEFORE aggregation: 128 -> 32) ----
  k_dense1<<<(N_NODES + 255) / 256, 256, 0, stream>>>(x, W1_1, W2_1, tA, sS);

  const int GCS_GRID = (N_NODES * 32 + 255) / 256;
  // layer 1 (+ layer-2 dense), layer 2 (+ layer-3 dense), layer 3 (combine only)
  k_gcs<0><<<GCS_GRID, 256, 0, stream>>>(rowinfo, edges, tA, sS, b_1, W1_2, W2_2, tB, nullptr);
  k_gcs<0><<<GCS_GRID, 256, 0, stream>>>(rowinfo, edges, tB, sS, b_2, W1_3, W2_3, tA, nullptr);
  k_gcs<1><<<GCS_GRID, 256, 0, stream>>>(rowinfo, edges, tA, sS, b_3, nullptr, nullptr, nullptr, hbuf);

  // ---- pool + head + softmax ----
  k_head<<<N_GRAPHS, 64, 0, stream>>>(hbuf, seg, Wd, bd, out);
}